// Round 8
// baseline (219.037 us; speedup 1.0000x reference)
//
#include <hip/hip_runtime.h>

typedef unsigned short u16;
typedef __bf16 bf16x8 __attribute__((ext_vector_type(8)));
typedef float f32x4 __attribute__((ext_vector_type(4)));
typedef u16 u16x8 __attribute__((ext_vector_type(8)));
typedef u16 u16x4 __attribute__((ext_vector_type(4)));

typedef const __attribute__((address_space(1))) void* as1_cvp;
typedef __attribute__((address_space(3))) void* as3_vp;

__device__ __forceinline__ void async_cp16(const void* g, void* l) {
  __builtin_amdgcn_global_load_lds((as1_cvp)g, (as3_vp)l, 16, 0, 0);
}

__device__ __forceinline__ u16 f2bf(float f) {
  union { float f; unsigned u; } x; x.f = f;
  unsigned r = x.u + 0x7fffu + ((x.u >> 16) & 1u);
  return (u16)(r >> 16);
}

__device__ __forceinline__ float bf2f(u16 v) {
  union { unsigned u; float f; } x; x.u = ((unsigned)v) << 16;
  return x.f;
}

__device__ __constant__ float c_lut[16] = {
  0.0f, 1.0f, -1.0f, 0.5f, -0.5f, 0.333333f, -0.333333f, 0.2f, -0.2f,
  0.142857f, -0.142857f, 0.090909f, -0.090909f, 0.076923f, -0.076923f, 0.0f };

// ---------------- fused prep A: cvt x -> bf16, maxabs(w_attn), maxabs(w_proj) ----
__global__ void prep_a(const float* __restrict__ wA, const float* __restrict__ wP,
                       const float* __restrict__ x, u16* __restrict__ xbf,
                       unsigned* __restrict__ scales) {
  const int bx = blockIdx.x;
  if (bx < 4096) {  // cvt 4194304 floats
    int i = bx * 1024 + threadIdx.x * 4;
    float4 v = *(const float4*)(x + i);
    u16x4 r; r.x = f2bf(v.x); r.y = f2bf(v.y); r.z = f2bf(v.z); r.w = f2bf(v.w);
    *(u16x4*)(xbf + i) = r;
    return;
  }
  const bool isA = bx < 4160;
  const float* w = isA ? wA : wP;
  const int n = isA ? 3145728 : 1048576;
  unsigned* o = scales + (isA ? 0 : 1);
  float m = 0.f;
  for (int i = ((bx - (isA ? 4096 : 4160)) * 256 + threadIdx.x) * 4; i < n; i += 65536) {
    float4 v = *(const float4*)(w + i);
    m = fmaxf(fmaxf(fabsf(v.x), fabsf(v.y)), fmaxf(fmaxf(fabsf(v.z), fabsf(v.w)), m));
  }
  for (int off = 32; off > 0; off >>= 1)
    m = fmaxf(m, __shfl_down(m, off, 64));
  __shared__ float sm[4];
  if ((threadIdx.x & 63) == 0) sm[threadIdx.x >> 6] = m;
  __syncthreads();
  if (threadIdx.x == 0) {
    m = fmaxf(fmaxf(sm[0], sm[1]), fmaxf(sm[2], sm[3]));
    atomicMax(o, __float_as_uint(m));  // nonneg floats: uint order == float order
  }
}

// ---------------- fused prep B: snap both weight matrices to LUT, emit bf16 ----
__global__ void prep_b(const float* __restrict__ wA, const float* __restrict__ wP,
                       u16* __restrict__ oA, u16* __restrict__ oP,
                       const unsigned* __restrict__ scales) {
  int i = (blockIdx.x * 256 + threadIdx.x) * 4;
  const float* w; u16* o; float scale;
  if (i < 3145728) { w = wA; o = oA; scale = __uint_as_float(scales[0]) + 1e-6f; }
  else { i -= 3145728; w = wP; o = oP; scale = __uint_as_float(scales[1]) + 1e-6f; }
  float4 v = *(const float4*)(w + i);
  float vv[4] = {v.x, v.y, v.z, v.w};
  u16x4 r;
#pragma unroll
  for (int e = 0; e < 4; e++) {
    float wn = vv[e] / scale;
    float best = 1e30f; int bi = 0;
#pragma unroll
    for (int jj = 0; jj < 16; jj++) {
      float d = fabsf(wn - c_lut[jj]);
      if (d < best) { best = d; bi = jj; }
    }
    r[e] = f2bf(c_lut[bi] * scale);
  }
  *(u16x4*)(o + i) = r;
}

// ---------------- GEMM: C[M,N] = A[M,K] * B[N,K]^T + bias ----------------
// Block tile: (MI*32) x 128, BK=64, double-buffered LDS, ONE barrier per
// K-step (prefetch issued before compute, overlaps the whole compute phase).
// XOR-source-swizzled staging, matching swizzled ds_read_b128 fragments.
// GEMM1 (vTout != null): cols<1024 (Q) scaled by log2e/8; cols>=2048 (V)
// written TRANSPOSED to vTout. ldc = row stride of outb/outf.
template<int MI>
__global__ __launch_bounds__(256, MI == 4 ? 2 : 3)
void gemm_bt(const u16* __restrict__ A, const u16* __restrict__ B,
             const float* __restrict__ bias, u16* __restrict__ outb,
             float* __restrict__ outf, u16* __restrict__ vTout,
             int M, int N, int K, int ldc) {
  __shared__ __align__(16) u16 lA[2][MI * 32 * 64];
  __shared__ __align__(16) u16 lB[2][128 * 64];
  const int t = threadIdx.x;
  const int lane = t & 63, wave = t >> 6;
  const int wm = wave >> 1, wn = wave & 1;
  const int quad = lane >> 4, l16 = lane & 15;
  const int ph = l16 & 7;
  const int m0 = blockIdx.y * (MI * 32), n0 = blockIdx.x * 128;
  const int srow = t >> 3, schunk = t & 7;

  auto stage = [&](int ki, int buf) {
    const int k0 = ki * 64;
#pragma unroll
    for (int i = 0; i < MI; i++) {
      int row = i * 32 + srow;
      int col = k0 + (schunk ^ (row & 7)) * 8;
      async_cp16(A + (size_t)(m0 + row) * K + col, &lA[buf][i * 2048 + t * 8]);
    }
#pragma unroll
    for (int i = 0; i < 4; i++) {
      int row = i * 32 + srow;
      int col = k0 + (schunk ^ (row & 7)) * 8;
      async_cp16(B + (size_t)(n0 + row) * K + col, &lB[buf][i * 2048 + t * 8]);
    }
  };

  f32x4 acc[MI][4] = {};
  stage(0, 0);
  const int KI = K >> 6;  // BK=64
  for (int ki = 0; ki < KI; ki++) {
    const int buf = ki & 1;
    __syncthreads();  // drains stage(ki); prev iter's reads of buf^1 done
    if (ki + 1 < KI) stage(ki + 1, buf ^ 1);
#pragma unroll
    for (int ks = 0; ks < 2; ks++) {
      bf16x8 af[MI], bfr[4];
#pragma unroll
      for (int mi = 0; mi < MI; mi++)
        af[mi] = *(const bf16x8*)&lA[buf][(wm * (MI * 16) + mi * 16 + l16) * 64 + ((ks * 4 + quad) ^ ph) * 8];
#pragma unroll
      for (int ni = 0; ni < 4; ni++)
        bfr[ni] = *(const bf16x8*)&lB[buf][(wn * 64 + ni * 16 + l16) * 64 + ((ks * 4 + quad) ^ ph) * 8];
#pragma unroll
      for (int mi = 0; mi < MI; mi++)
#pragma unroll
        for (int ni = 0; ni < 4; ni++)
          acc[mi][ni] = __builtin_amdgcn_mfma_f32_16x16x32_bf16(af[mi], bfr[ni], acc[mi][ni], 0, 0, 0);
    }
  }

#pragma unroll
  for (int mi = 0; mi < MI; mi++) {
    const int rowb = m0 + wm * (MI * 16) + mi * 16 + quad * 4;
#pragma unroll
    for (int ni = 0; ni < 4; ni++) {
      const int col = n0 + wn * 64 + ni * 16 + l16;
      const float bb = bias[col];
      const float mult = (vTout && col < 1024) ? 0.180336880f : 1.0f;  // log2(e)/8
      if (vTout && col >= 2048) {
        u16x4 pk;
#pragma unroll
        for (int r = 0; r < 4; r++) pk[r] = f2bf(acc[mi][ni][r] + bb);
        *(u16x4*)&vTout[(size_t)(rowb >> 11) * 2097152 + (size_t)(col - 2048) * 2048 + (rowb & 2047)] = pk;
      } else {
#pragma unroll
        for (int r = 0; r < 4; r++) {
          float v = (acc[mi][ni][r] + bb) * mult;
          if (outb) outb[(size_t)(rowb + r) * ldc + col] = f2bf(v);
          else      outf[(size_t)(rowb + r) * ldc + col] = v;
        }
      }
    }
  }
}

// ---------------- causal flash attention, uniform split-kv ----------------
// No-max softmax is LINEAR in kv: partial (O,l) over disjoint kv ranges add.
// Block (pair, half, bh) handles q-tiles qtB=15-pair and qtA=pair, each over
// half of its kv range -> exactly 17 kv-tile visits per block (uniform).
// Partials: O (bf16, un-normalized) + l (fp32) per half; combined by norm_kernel.
__device__ __forceinline__ void do_visit(
    const u16* sKc, const u16* sVc, u16* sP, const bf16x8 (&aq)[2][2],
    f32x4 (&acc)[2][4], f32x4 (&accl)[2], bf16x8 onesf,
    int kv0, int qt, int w, int quad, int l16, int ph) {
  const int wrow0 = qt * 128 + w * 32;
  if (kv0 > wrow0 + 31) return;  // wave fully masked in this tile
  f32x4 s[2][4] = {};
#pragma unroll
  for (int ks = 0; ks < 2; ks++) {
#pragma unroll
    for (int ni = 0; ni < 4; ni++) {
      bf16x8 bk = *(const bf16x8*)&sKc[(ni * 16 + l16) * 64 + ((ks * 4 + quad) ^ ph) * 8];
#pragma unroll
      for (int mi = 0; mi < 2; mi++)
        s[mi][ni] = __builtin_amdgcn_mfma_f32_16x16x32_bf16(aq[mi][ks], bk, s[mi][ni], 0, 0, 0);
    }
  }
  if (kv0 + 63 > wrow0) {  // diagonal region: causal mask
#pragma unroll
    for (int mi = 0; mi < 2; mi++)
#pragma unroll
      for (int ni = 0; ni < 4; ni++)
#pragma unroll
        for (int r = 0; r < 4; r++)
          if ((kv0 + ni * 16 + l16) > (wrow0 + mi * 16 + quad * 4 + r)) s[mi][ni][r] = -1e30f;
  }
#pragma unroll
  for (int mi = 0; mi < 2; mi++)
#pragma unroll
    for (int ni = 0; ni < 4; ni++)
#pragma unroll
      for (int r = 0; r < 4; r++) {
        float p = __builtin_amdgcn_exp2f(s[mi][ni][r]);
        sP[(w * 32 + mi * 16 + quad * 4 + r) * 72 + ni * 16 + l16] = (u16)(__float_as_uint(p) >> 16);
      }
  __asm__ volatile("s_waitcnt lgkmcnt(0)" ::: "memory");  // sP rows wave-private
#pragma unroll
  for (int ks = 0; ks < 2; ks++) {
#pragma unroll
    for (int mi = 0; mi < 2; mi++) {
      bf16x8 ap = *(const bf16x8*)&sP[(w * 32 + mi * 16 + l16) * 72 + ks * 32 + quad * 8];
#pragma unroll
      for (int ni = 0; ni < 4; ni++) {
        bf16x8 bv = *(const bf16x8*)&sVc[(ni * 16 + l16) * 64 + ((ks * 4 + quad) ^ ph) * 8];
        acc[mi][ni] = __builtin_amdgcn_mfma_f32_16x16x32_bf16(ap, bv, acc[mi][ni], 0, 0, 0);
      }
      accl[mi] = __builtin_amdgcn_mfma_f32_16x16x32_bf16(ap, onesf, accl[mi], 0, 0, 0);
    }
  }
}

__device__ __forceinline__ void epilogue_tile(
    const f32x4 (&acc)[2][4], const f32x4 (&accl)[2], int qt, int b, int h,
    u16* __restrict__ O, float* __restrict__ L, int w, int quad, int l16) {
#pragma unroll
  for (int mi = 0; mi < 2; mi++)
#pragma unroll
    for (int r = 0; r < 4; r++) {
      const int q = qt * 128 + w * 32 + mi * 16 + quad * 4 + r;
      const size_t orow = (size_t)(b * 2048 + q) * 1024 + h * 64;
#pragma unroll
      for (int ni = 0; ni < 4; ni++)
        O[orow + ni * 16 + l16] = f2bf(acc[mi][ni][r]);
      if (l16 == 0) L[(b * 16 + h) * 2048 + q] = accl[mi][r];
    }
}

__global__ __launch_bounds__(256, 2)
void attn_kernel(const u16* __restrict__ qk, const u16* __restrict__ vT,
                 u16* __restrict__ O0, u16* __restrict__ O1,
                 float* __restrict__ L0, float* __restrict__ L1) {
  // u16 offsets: sK[2] 0..8191 | sVt[2] 8192..16383 | sQ 16384..32767 (2 tiles,
  // prologue only) aliased with sP 16384..25599 (128*72). Total 64 KB.
  __shared__ __align__(16) u16 lds[32768];
  u16* const sK  = lds;
  u16* const sVt = lds + 8192;
  u16* const sQ  = lds + 16384;
  u16* const sP  = lds + 16384;

  const int t = threadIdx.x;
  const int lane = t & 63, w = t >> 6;
  const int quad = lane >> 4, l16 = lane & 15;
  const int ph = l16 & 7;
  const int pair = blockIdx.x >> 1, half = blockIdx.x & 1;
  const int qtB = 15 - pair, qtA = pair;
  const int nB = 16 - pair, nA = pair + 1;       // nB + nA = 17
  const int startB = half * nB, startA = half * nA;
  const int bh = blockIdx.y;
  const int b = bh >> 4, h = bh & 15;

  const size_t qkbase = (size_t)(b * 2048) * 2048 + h * 64;
  const size_t vtbase = ((size_t)(b * 1024 + h * 64)) * 2048;
  const int srow = t >> 3, schunk = t & 7;

  auto prefetch = [&](int j, int buf) {
    const int kv1 = j * 64;
#pragma unroll
    for (int i = 0; i < 2; i++) {
      int row = i * 32 + srow;
      int colk = 1024 + (schunk ^ (row & 7)) * 8;
      async_cp16(qk + qkbase + (size_t)(kv1 + row) * 2048 + colk, sK + buf + i * 2048 + t * 8);
    }
#pragma unroll
    for (int i = 0; i < 2; i++) {
      int d = i * 32 + srow;
      int colv = kv1 + (schunk ^ (d & 7)) * 8;
      async_cp16(vT + vtbase + (size_t)d * 2048 + colv, sVt + buf + i * 2048 + t * 8);
    }
  };

  // prologue: stage Q of both tiles + K/V of visit 0
#pragma unroll
  for (int tile = 0; tile < 2; tile++) {
    const int q0 = (tile ? qtA : qtB) * 128;
#pragma unroll
    for (int i = 0; i < 4; i++) {
      int row = i * 32 + srow;
      int col = (schunk ^ (row & 7)) * 8;
      async_cp16(qk + qkbase + (size_t)(q0 + row) * 2048 + col,
                 sQ + tile * 8192 + i * 2048 + t * 8);
    }
  }
  prefetch(startB, 0);
  __syncthreads();

  bf16x8 aqB[2][2], aqA[2][2];
#pragma unroll
  for (int mi = 0; mi < 2; mi++)
#pragma unroll
    for (int ks = 0; ks < 2; ks++) {
      aqB[mi][ks] = *(const bf16x8*)&sQ[(w * 32 + mi * 16 + l16) * 64 + ((ks * 4 + quad) ^ ph) * 8];
      aqA[mi][ks] = *(const bf16x8*)&sQ[8192 + (w * 32 + mi * 16 + l16) * 64 + ((ks * 4 + quad) ^ ph) * 8];
    }
  __syncthreads();  // Q in regs everywhere; sP region writable

  f32x4 accB[2][4] = {}, accA[2][4] = {};
  f32x4 acclB[2] = {}, acclA[2] = {};
  u16x8 onesu = {};
  if (l16 == 0) {
#pragma unroll
    for (int i2 = 0; i2 < 8; i2++) onesu[i2] = 0x3F80;  // bf16 1.0
  }
  bf16x8 onesf = *(bf16x8*)&onesu;

  for (int v = 0; v < 17; v++) {
    const int cur = (v & 1) * 4096;
    if (v + 1 < 17) {
      const int jn = (v + 1 < nB) ? (startB + v + 1) : (startA + (v + 1 - nB));
      prefetch(jn, ((v + 1) & 1) * 4096);
    }
    if (v < nB)
      do_visit(sK + cur, sVt + cur, sP, aqB, accB, acclB, onesf,
               (startB + v) * 64, qtB, w, quad, l16, ph);
    else
      do_visit(sK + cur, sVt + cur, sP, aqA, accA, acclA, onesf,
               (startA + v - nB) * 64, qtA, w, quad, l16, ph);
    __syncthreads();  // all waves done with cur; prefetch drained for v+1
  }

  u16* Op = half ? O1 : O0;
  float* Lp = half ? L1 : L0;
  epilogue_tile(accB, acclB, qtB, b, h, Op, Lp, w, quad, l16);
  epilogue_tile(accA, acclA, qtA, b, h, Op, Lp, w, quad, l16);
}

// ---------------- combine partials: y = (O0+O1)/(l0+l1), in place over O1 ----
__global__ void norm_kernel(const u16* __restrict__ O0, u16* __restrict__ O1y,
                            const float* __restrict__ L0, const float* __restrict__ L1) {
  const int i = (blockIdx.x * 256 + threadIdx.x) * 8;
  const int row = i >> 10, col = i & 1023;
  const int b = row >> 11, q = row & 2047, h = col >> 6;
  const int li = (b * 16 + h) * 2048 + q;
  const float inv = 1.0f / (L0[li] + L1[li]);
  u16x8 a = *(const u16x8*)(O0 + i);
  u16x8 c = *(const u16x8*)(O1y + i);
  u16x8 r;
#pragma unroll
  for (int e = 0; e < 8; e++)
    r[e] = f2bf((bf2f(a[e]) + bf2f(c[e])) * inv);
  *(u16x8*)(O1y + i) = r;
}

extern "C" void kernel_launch(void* const* d_in, const int* in_sizes, int n_in,
                              void* d_out, int out_size, void* d_ws, size_t ws_size,
                              hipStream_t stream) {
  const float* x      = (const float*)d_in[0];
  const float* w_attn = (const float*)d_in[1];
  const float* b_attn = (const float*)d_in[2];
  const float* w_proj = (const float*)d_in[3];
  const float* b_proj = (const float*)d_in[4];
  float* out = (float*)d_out;

  char* ws = (char*)d_ws;
  unsigned* scales = (unsigned*)ws;
  u16* wAq = (u16*)(ws + 64);
  u16* wPq = (u16*)(ws + 64 + 6291456);
  u16* xbf = (u16*)(ws + 64 + 6291456 + 2097152);
  u16* qk  = (u16*)(ws + 64 + 6291456 + 2097152 + 8388608);
  u16* ybf = (u16*)(ws + 64 + 6291456 + 2097152 + 8388608 + 16777216);
  u16* vT  = (u16*)(ws + 64 + 6291456 + 2097152 + 8388608 + 16777216 + 8388608);

  // region reuse after GEMM1: xbf -> O0 partial, ybf -> O1 partial (normalized
  // in place -> ybf), wAq -> L0/L1 (fp32, 256 KB each).
  u16* O0 = xbf;
  u16* O1 = ybf;
  float* L0 = (float*)(ws + 64);
  float* L1 = (float*)(ws + 64 + 1048576);

  (void)hipMemsetAsync(ws, 0, 8, stream);
  prep_a<<<4224, 256, 0, stream>>>(w_attn, w_proj, x, xbf, scales);
  prep_b<<<4096, 256, 0, stream>>>(w_attn, w_proj, wAq, wPq, scales);

  dim3 g1(24, 32);   // N=3072/128, M=4096/128
  gemm_bt<4><<<g1, 256, 0, stream>>>(xbf, wAq, b_attn, qk, nullptr, vT, 4096, 3072, 1024, 2048);

  dim3 ga(16, 32);   // (pair,half) x (b,h): 512 uniform blocks, 17 visits each
  attn_kernel<<<ga, 256, 0, stream>>>(qk, vT, O0, O1, L0, L1);
  norm_kernel<<<2048, 256, 0, stream>>>(O0, O1, L0, L1);

  dim3 g2(8, 64);    // N=1024/128, M=4096/64
  gemm_bt<2><<<g2, 256, 0, stream>>>(ybf, wPq, b_proj, nullptr, out, nullptr, 4096, 1024, 1024, 1024);
}

// Round 10
// 203.336 us; speedup vs baseline: 1.0772x; 1.0772x over previous
//
#include <hip/hip_runtime.h>

typedef unsigned short u16;
typedef __bf16 bf16x8 __attribute__((ext_vector_type(8)));
typedef float f32x4 __attribute__((ext_vector_type(4)));
typedef u16 u16x8 __attribute__((ext_vector_type(8)));
typedef u16 u16x4 __attribute__((ext_vector_type(4)));

typedef const __attribute__((address_space(1))) void* as1_cvp;
typedef __attribute__((address_space(3))) void* as3_vp;

__device__ __forceinline__ void async_cp16(const void* g, void* l) {
  __builtin_amdgcn_global_load_lds((as1_cvp)g, (as3_vp)l, 16, 0, 0);
}

__device__ __forceinline__ u16 f2bf(float f) {
  union { float f; unsigned u; } x; x.f = f;
  unsigned r = x.u + 0x7fffu + ((x.u >> 16) & 1u);
  return (u16)(r >> 16);
}

__device__ __forceinline__ float bf2f(u16 v) {
  union { unsigned u; float f; } x; x.u = ((unsigned)v) << 16;
  return x.f;
}

__device__ __constant__ float c_lut[16] = {
  0.0f, 1.0f, -1.0f, 0.5f, -0.5f, 0.333333f, -0.333333f, 0.2f, -0.2f,
  0.142857f, -0.142857f, 0.090909f, -0.090909f, 0.076923f, -0.076923f, 0.0f };

// ---------------- fused prep A: cvt x -> bf16, maxabs(w_attn), maxabs(w_proj) ----
__global__ void prep_a(const float* __restrict__ wA, const float* __restrict__ wP,
                       const float* __restrict__ x, u16* __restrict__ xbf,
                       unsigned* __restrict__ scales) {
  const int bx = blockIdx.x;
  if (bx < 4096) {  // cvt 4194304 floats
    int i = bx * 1024 + threadIdx.x * 4;
    float4 v = *(const float4*)(x + i);
    u16x4 r; r.x = f2bf(v.x); r.y = f2bf(v.y); r.z = f2bf(v.z); r.w = f2bf(v.w);
    *(u16x4*)(xbf + i) = r;
    return;
  }
  const bool isA = bx < 4160;
  const float* w = isA ? wA : wP;
  const int n = isA ? 3145728 : 1048576;
  unsigned* o = scales + (isA ? 0 : 1);
  float m = 0.f;
  for (int i = ((bx - (isA ? 4096 : 4160)) * 256 + threadIdx.x) * 4; i < n; i += 65536) {
    float4 v = *(const float4*)(w + i);
    m = fmaxf(fmaxf(fabsf(v.x), fabsf(v.y)), fmaxf(fmaxf(fabsf(v.z), fabsf(v.w)), m));
  }
  for (int off = 32; off > 0; off >>= 1)
    m = fmaxf(m, __shfl_down(m, off, 64));
  __shared__ float sm[4];
  if ((threadIdx.x & 63) == 0) sm[threadIdx.x >> 6] = m;
  __syncthreads();
  if (threadIdx.x == 0) {
    m = fmaxf(fmaxf(sm[0], sm[1]), fmaxf(sm[2], sm[3]));
    atomicMax(o, __float_as_uint(m));  // nonneg floats: uint order == float order
  }
}

// ---------------- fused prep B: snap both weight matrices to LUT, emit bf16 ----
__global__ void prep_b(const float* __restrict__ wA, const float* __restrict__ wP,
                       u16* __restrict__ oA, u16* __restrict__ oP,
                       const unsigned* __restrict__ scales) {
  int i = (blockIdx.x * 256 + threadIdx.x) * 4;
  const float* w; u16* o; float scale;
  if (i < 3145728) { w = wA; o = oA; scale = __uint_as_float(scales[0]) + 1e-6f; }
  else { i -= 3145728; w = wP; o = oP; scale = __uint_as_float(scales[1]) + 1e-6f; }
  float4 v = *(const float4*)(w + i);
  float vv[4] = {v.x, v.y, v.z, v.w};
  u16x4 r;
#pragma unroll
  for (int e = 0; e < 4; e++) {
    float wn = vv[e] / scale;
    float best = 1e30f; int bi = 0;
#pragma unroll
    for (int jj = 0; jj < 16; jj++) {
      float d = fabsf(wn - c_lut[jj]);
      if (d < best) { best = d; bi = jj; }
    }
    r[e] = f2bf(c_lut[bi] * scale);
  }
  *(u16x4*)(o + i) = r;
}

// ---------------- GEMM: C[M,N] = A[M,K] * B[N,K]^T + bias ----------------
// Block tile: (MI*32) x 128, BK=32, double-buffered LDS (32 KB MI=4 ->
// 4+ blocks/CU), ONE barrier per K-step, prefetch issued before compute.
// Sub-block = 64 rows x 32 cols = 2048 u16. Source-swizzled staging:
// LDS slot s of row r holds global chunk s ^ ((r>>1)&3); reader fetches
// slot quad ^ ((rr>>1)&3) = chunk quad -> 2-way (free) b128 reads.
// GEMM1 (vTout != null): cols<1024 (Q) scaled by log2e/8; cols>=2048 (V)
// written TRANSPOSED to vTout. ldc = row stride of outb/outf.
template<int MI>
__global__ __launch_bounds__(256, 4)
void gemm_bt(const u16* __restrict__ A, const u16* __restrict__ B,
             const float* __restrict__ bias, u16* __restrict__ outb,
             float* __restrict__ outf, u16* __restrict__ vTout,
             int M, int N, int K, int ldc) {
  __shared__ __align__(16) u16 lA[2][MI * 1024];   // MI/2 sub-blocks of 2048
  __shared__ __align__(16) u16 lB[2][4096];        // 2 sub-blocks of 2048
  const int t = threadIdx.x;
  const int lane = t & 63, wave = t >> 6;
  const int wm = wave >> 1, wn = wave & 1;
  const int quad = lane >> 4, l16 = lane & 15;
  const int m0 = blockIdx.y * (MI * 32), n0 = blockIdx.x * 128;

  const int r0 = t >> 2, sst = t & 3;
  const int schunk = sst ^ ((r0 >> 1) & 3);        // source chunk for this lane

  auto stage = [&](int ki, int buf) {
    const int col = ki * 32 + schunk * 8;
#pragma unroll
    for (int i = 0; i < MI / 2; i++)
      async_cp16(A + (size_t)(m0 + i * 64 + r0) * K + col, &lA[buf][i * 2048 + t * 8]);
#pragma unroll
    for (int i = 0; i < 2; i++)
      async_cp16(B + (size_t)(n0 + i * 64 + r0) * K + col, &lB[buf][i * 2048 + t * 8]);
  };

  f32x4 acc[MI][4] = {};
  stage(0, 0);
  const int KI = K >> 5;  // BK=32
  for (int ki = 0; ki < KI; ki++) {
    const int buf = ki & 1;
    __syncthreads();  // drains stage(ki); prev iter's reads of buf^1 done
    if (ki + 1 < KI) stage(ki + 1, buf ^ 1);
    bf16x8 af[MI], bfr[4];
#pragma unroll
    for (int mi = 0; mi < MI; mi++) {
      const int rA = wm * (MI * 16) + mi * 16 + l16;
      const int iA = rA >> 6, rr = rA & 63;
      af[mi] = *(const bf16x8*)&lA[buf][iA * 2048 + rr * 32 + (quad ^ ((rr >> 1) & 3)) * 8];
    }
#pragma unroll
    for (int ni = 0; ni < 4; ni++) {
      const int rr = ni * 16 + l16;
      bfr[ni] = *(const bf16x8*)&lB[buf][wn * 2048 + rr * 32 + (quad ^ ((rr >> 1) & 3)) * 8];
    }
#pragma unroll
    for (int mi = 0; mi < MI; mi++)
#pragma unroll
      for (int ni = 0; ni < 4; ni++)
        acc[mi][ni] = __builtin_amdgcn_mfma_f32_16x16x32_bf16(af[mi], bfr[ni], acc[mi][ni], 0, 0, 0);
  }

#pragma unroll
  for (int mi = 0; mi < MI; mi++) {
    const int rowb = m0 + wm * (MI * 16) + mi * 16 + quad * 4;
#pragma unroll
    for (int ni = 0; ni < 4; ni++) {
      const int col = n0 + wn * 64 + ni * 16 + l16;
      const float bb = bias[col];
      const float mult = (vTout && col < 1024) ? 0.180336880f : 1.0f;  // log2(e)/8
      if (vTout && col >= 2048) {
        u16x4 pk;
#pragma unroll
        for (int r = 0; r < 4; r++) pk[r] = f2bf(acc[mi][ni][r] + bb);
        *(u16x4*)&vTout[(size_t)(rowb >> 11) * 2097152 + (size_t)(col - 2048) * 2048 + (rowb & 2047)] = pk;
      } else {
#pragma unroll
        for (int r = 0; r < 4; r++) {
          float v = (acc[mi][ni][r] + bb) * mult;
          if (outb) outb[(size_t)(rowb + r) * ldc + col] = f2bf(v);
          else      outf[(size_t)(rowb + r) * ldc + col] = v;
        }
      }
    }
  }
}

// ---------------- causal flash attention, uniform split-kv ----------------
// No-max softmax is LINEAR in kv: partial (O,l) over disjoint kv ranges add.
// Block (pair, half, bh) handles q-tiles qtB=15-pair and qtA=pair, each over
// half of its kv range -> exactly 17 kv-tile visits per block (uniform).
// Partials: O (bf16, un-normalized) + l (fp32) per half; combined by norm_kernel.
__device__ __forceinline__ void do_visit(
    const u16* sKc, const u16* sVc, u16* sP, const bf16x8 (&aq)[2][2],
    f32x4 (&acc)[2][4], f32x4 (&accl)[2], bf16x8 onesf,
    int kv0, int qt, int w, int quad, int l16, int ph) {
  const int wrow0 = qt * 128 + w * 32;
  if (kv0 > wrow0 + 31) return;  // wave fully masked in this tile
  f32x4 s[2][4] = {};
#pragma unroll
  for (int ks = 0; ks < 2; ks++) {
#pragma unroll
    for (int ni = 0; ni < 4; ni++) {
      bf16x8 bk = *(const bf16x8*)&sKc[(ni * 16 + l16) * 64 + ((ks * 4 + quad) ^ ph) * 8];
#pragma unroll
      for (int mi = 0; mi < 2; mi++)
        s[mi][ni] = __builtin_amdgcn_mfma_f32_16x16x32_bf16(aq[mi][ks], bk, s[mi][ni], 0, 0, 0);
    }
  }
  if (kv0 + 63 > wrow0) {  // diagonal region: causal mask
#pragma unroll
    for (int mi = 0; mi < 2; mi++)
#pragma unroll
      for (int ni = 0; ni < 4; ni++)
#pragma unroll
        for (int r = 0; r < 4; r++)
          if ((kv0 + ni * 16 + l16) > (wrow0 + mi * 16 + quad * 4 + r)) s[mi][ni][r] = -1e30f;
  }
#pragma unroll
  for (int mi = 0; mi < 2; mi++)
#pragma unroll
    for (int ni = 0; ni < 4; ni++)
#pragma unroll
      for (int r = 0; r < 4; r++) {
        float p = __builtin_amdgcn_exp2f(s[mi][ni][r]);
        sP[(w * 32 + mi * 16 + quad * 4 + r) * 72 + ni * 16 + l16] = (u16)(__float_as_uint(p) >> 16);
      }
  __asm__ volatile("s_waitcnt lgkmcnt(0)" ::: "memory");  // sP rows wave-private
#pragma unroll
  for (int ks = 0; ks < 2; ks++) {
#pragma unroll
    for (int mi = 0; mi < 2; mi++) {
      bf16x8 ap = *(const bf16x8*)&sP[(w * 32 + mi * 16 + l16) * 72 + ks * 32 + quad * 8];
#pragma unroll
      for (int ni = 0; ni < 4; ni++) {
        bf16x8 bv = *(const bf16x8*)&sVc[(ni * 16 + l16) * 64 + ((ks * 4 + quad) ^ ph) * 8];
        acc[mi][ni] = __builtin_amdgcn_mfma_f32_16x16x32_bf16(ap, bv, acc[mi][ni], 0, 0, 0);
      }
      accl[mi] = __builtin_amdgcn_mfma_f32_16x16x32_bf16(ap, onesf, accl[mi], 0, 0, 0);
    }
  }
}

__device__ __forceinline__ void epilogue_tile(
    const f32x4 (&acc)[2][4], const f32x4 (&accl)[2], int qt, int b, int h,
    u16* __restrict__ O, float* __restrict__ L, int w, int quad, int l16) {
#pragma unroll
  for (int mi = 0; mi < 2; mi++)
#pragma unroll
    for (int r = 0; r < 4; r++) {
      const int q = qt * 128 + w * 32 + mi * 16 + quad * 4 + r;
      const size_t orow = (size_t)(b * 2048 + q) * 1024 + h * 64;
#pragma unroll
      for (int ni = 0; ni < 4; ni++)
        O[orow + ni * 16 + l16] = f2bf(acc[mi][ni][r]);
      if (l16 == 0) L[(b * 16 + h) * 2048 + q] = accl[mi][r];
    }
}

__global__ __launch_bounds__(256, 2)
void attn_kernel(const u16* __restrict__ qk, const u16* __restrict__ vT,
                 u16* __restrict__ O0, u16* __restrict__ O1,
                 float* __restrict__ L0, float* __restrict__ L1) {
  // u16 offsets: sK[2] 0..8191 | sVt[2] 8192..16383 | sQ 16384..32767 (2 tiles,
  // prologue only) aliased with sP 16384..25599 (128*72). Total 64 KB.
  __shared__ __align__(16) u16 lds[32768];
  u16* const sK  = lds;
  u16* const sVt = lds + 8192;
  u16* const sQ  = lds + 16384;
  u16* const sP  = lds + 16384;

  const int t = threadIdx.x;
  const int lane = t & 63, w = t >> 6;
  const int quad = lane >> 4, l16 = lane & 15;
  const int ph = l16 & 7;
  const int pair = blockIdx.x >> 1, half = blockIdx.x & 1;
  const int qtB = 15 - pair, qtA = pair;
  const int nB = 16 - pair, nA = pair + 1;       // nB + nA = 17
  const int startB = half * nB, startA = half * nA;
  const int bh = blockIdx.y;
  const int b = bh >> 4, h = bh & 15;

  const size_t qkbase = (size_t)(b * 2048) * 2048 + h * 64;
  const size_t vtbase = ((size_t)(b * 1024 + h * 64)) * 2048;
  const int srow = t >> 3, schunk = t & 7;

  auto prefetch = [&](int j, int buf) {
    const int kv1 = j * 64;
#pragma unroll
    for (int i = 0; i < 2; i++) {
      int row = i * 32 + srow;
      int colk = 1024 + (schunk ^ (row & 7)) * 8;
      async_cp16(qk + qkbase + (size_t)(kv1 + row) * 2048 + colk, sK + buf + i * 2048 + t * 8);
    }
#pragma unroll
    for (int i = 0; i < 2; i++) {
      int d = i * 32 + srow;
      int colv = kv1 + (schunk ^ (d & 7)) * 8;
      async_cp16(vT + vtbase + (size_t)d * 2048 + colv, sVt + buf + i * 2048 + t * 8);
    }
  };

  // prologue: stage Q of both tiles + K/V of visit 0
#pragma unroll
  for (int tile = 0; tile < 2; tile++) {
    const int q0 = (tile ? qtA : qtB) * 128;
#pragma unroll
    for (int i = 0; i < 4; i++) {
      int row = i * 32 + srow;
      int col = (schunk ^ (row & 7)) * 8;
      async_cp16(qk + qkbase + (size_t)(q0 + row) * 2048 + col,
                 sQ + tile * 8192 + i * 2048 + t * 8);
    }
  }
  prefetch(startB, 0);
  __syncthreads();

  bf16x8 aqB[2][2], aqA[2][2];
#pragma unroll
  for (int mi = 0; mi < 2; mi++)
#pragma unroll
    for (int ks = 0; ks < 2; ks++) {
      aqB[mi][ks] = *(const bf16x8*)&sQ[(w * 32 + mi * 16 + l16) * 64 + ((ks * 4 + quad) ^ ph) * 8];
      aqA[mi][ks] = *(const bf16x8*)&sQ[8192 + (w * 32 + mi * 16 + l16) * 64 + ((ks * 4 + quad) ^ ph) * 8];
    }
  __syncthreads();  // Q in regs everywhere; sP region writable

  f32x4 accB[2][4] = {}, accA[2][4] = {};
  f32x4 acclB[2] = {}, acclA[2] = {};
  u16x8 onesu = {};
  if (l16 == 0) {
#pragma unroll
    for (int i2 = 0; i2 < 8; i2++) onesu[i2] = 0x3F80;  // bf16 1.0
  }
  bf16x8 onesf = *(bf16x8*)&onesu;

  for (int v = 0; v < 17; v++) {
    const int cur = (v & 1) * 4096;
    if (v + 1 < 17) {
      const int jn = (v + 1 < nB) ? (startB + v + 1) : (startA + (v + 1 - nB));
      prefetch(jn, ((v + 1) & 1) * 4096);
    }
    if (v < nB)
      do_visit(sK + cur, sVt + cur, sP, aqB, accB, acclB, onesf,
               (startB + v) * 64, qtB, w, quad, l16, ph);
    else
      do_visit(sK + cur, sVt + cur, sP, aqA, accA, acclA, onesf,
               (startA + v - nB) * 64, qtA, w, quad, l16, ph);
    __syncthreads();  // all waves done with cur; prefetch drained for v+1
  }

  u16* Op = half ? O1 : O0;
  float* Lp = half ? L1 : L0;
  epilogue_tile(accB, acclB, qtB, b, h, Op, Lp, w, quad, l16);
  epilogue_tile(accA, acclA, qtA, b, h, Op, Lp, w, quad, l16);
}

// ---------------- combine partials: y = (O0+O1)/(l0+l1), in place over O1 ----
__global__ void norm_kernel(const u16* __restrict__ O0, u16* __restrict__ O1y,
                            const float* __restrict__ L0, const float* __restrict__ L1) {
  const int i = (blockIdx.x * 256 + threadIdx.x) * 8;
  const int row = i >> 10, col = i & 1023;
  const int b = row >> 11, q = row & 2047, h = col >> 6;
  const int li = (b * 16 + h) * 2048 + q;
  const float inv = 1.0f / (L0[li] + L1[li]);
  u16x8 a = *(const u16x8*)(O0 + i);
  u16x8 c = *(const u16x8*)(O1y + i);
  u16x8 r;
#pragma unroll
  for (int e = 0; e < 8; e++)
    r[e] = f2bf((bf2f(a[e]) + bf2f(c[e])) * inv);
  *(u16x8*)(O1y + i) = r;
}

extern "C" void kernel_launch(void* const* d_in, const int* in_sizes, int n_in,
                              void* d_out, int out_size, void* d_ws, size_t ws_size,
                              hipStream_t stream) {
  const float* x      = (const float*)d_in[0];
  const float* w_attn = (const float*)d_in[1];
  const float* b_attn = (const float*)d_in[2];
  const float* w_proj = (const float*)d_in[3];
  const float* b_proj = (const float*)d_in[4];
  float* out = (float*)d_out;

  char* ws = (char*)d_ws;
  unsigned* scales = (unsigned*)ws;
  u16* wAq = (u16*)(ws + 64);
  u16* wPq = (u16*)(ws + 64 + 6291456);
  u16* xbf = (u16*)(ws + 64 + 6291456 + 2097152);
  u16* qk  = (u16*)(ws + 64 + 6291456 + 2097152 + 8388608);
  u16* ybf = (u16*)(ws + 64 + 6291456 + 2097152 + 8388608 + 16777216);
  u16* vT  = (u16*)(ws + 64 + 6291456 + 2097152 + 8388608 + 16777216 + 8388608);

  // region reuse after GEMM1: xbf -> O0 partial, ybf -> O1 partial (normalized
  // in place -> ybf), wAq -> L0/L1 (fp32, 256 KB each).
  u16* O0 = xbf;
  u16* O1 = ybf;
  float* L0 = (float*)(ws + 64);
  float* L1 = (float*)(ws + 64 + 1048576);

  (void)hipMemsetAsync(ws, 0, 8, stream);
  prep_a<<<4224, 256, 0, stream>>>(w_attn, w_proj, x, xbf, scales);
  prep_b<<<4096, 256, 0, stream>>>(w_attn, w_proj, wAq, wPq, scales);

  dim3 g1(24, 32);   // N=3072/128, M=4096/128
  gemm_bt<4><<<g1, 256, 0, stream>>>(xbf, wAq, b_attn, qk, nullptr, vT, 4096, 3072, 1024, 2048);

  dim3 ga(16, 32);   // (pair,half) x (b,h): 512 uniform blocks, 17 visits each
  attn_kernel<<<ga, 256, 0, stream>>>(qk, vT, O0, O1, L0, L1);
  norm_kernel<<<2048, 256, 0, stream>>>(O0, O1, L0, L1);

  dim3 g2(8, 64);    // N=1024/128, M=4096/64
  gemm_bt<2><<<g2, 256, 0, stream>>>(ybf, wPq, b_proj, nullptr, out, nullptr, 4096, 1024, 1024, 1024);
}